// Round 10
// baseline (2573.090 us; speedup 1.0000x reference)
//
#include <hip/hip_runtime.h>

typedef _Float16 half8 __attribute__((ext_vector_type(8)));
typedef _Float16 half2v __attribute__((ext_vector_type(2)));
typedef float floatx4 __attribute__((ext_vector_type(4)));

__device__ __forceinline__ float fast_rcp(float x) { return __builtin_amdgcn_rcpf(x); }
__device__ __forceinline__ float fast_sigmoid(float x) {
  return fast_rcp(1.f + __expf(-x));
}
__device__ __forceinline__ float fast_tanh(float x) {
  return 1.f - 2.f * fast_rcp(1.f + __expf(2.f * x));
}

// ---------------- prep: fp16 fragment-ordered weights + bias sums + prog zero ----------
// B-frag layout for mfma_f32_16x16x32_f16: lane L, reg j holds
// W[n = ntile*16 + (L&15)][k = ktile*32 + (L>>4)*8 + j].
__global__ void prep_kernel(const float* __restrict__ wih0, const float* __restrict__ whh0,
                            const float* __restrict__ bih0, const float* __restrict__ bhh0,
                            const float* __restrict__ wih1, const float* __restrict__ whh1,
                            const float* __restrict__ bih1, const float* __restrict__ bhh1,
                            _Float16* __restrict__ w0f, _Float16* __restrict__ w1f,
                            float* __restrict__ bias0, float* __restrict__ bias1,
                            int* __restrict__ prog)
{
  int stride = gridDim.x * blockDim.x;
  int idx0 = blockIdx.x * blockDim.x + threadIdx.x;
  const int N0 = 6*32*64*8;      // layer0: K=192 (x 64 | h 128)
  const int N1 = 8*32*64*8;      // layer1: K=256 (h1 128 | h 128)
  for (int e = idx0; e < N0 + N1 + 1024 + 128; e += stride) {
    if (e < N0) {
      int j = e & 7; int le = e >> 3; int lane = le & 63; int frag = le >> 6;
      int kt = frag >> 5, ntile = frag & 31;
      int n = ntile*16 + (lane & 15);
      int kk = kt*32 + ((lane >> 4) << 3) + j;
      float v = (kk < 64) ? wih0[n*64 + kk] : whh0[n*128 + (kk - 64)];
      w0f[e] = (_Float16)v;
    } else if (e < N0 + N1) {
      int e2 = e - N0;
      int j = e2 & 7; int le = e2 >> 3; int lane = le & 63; int frag = le >> 6;
      int kt = frag >> 5, ntile = frag & 31;
      int n = ntile*16 + (lane & 15);
      int kk = kt*32 + ((lane >> 4) << 3) + j;
      float v = (kk < 128) ? wih1[n*128 + kk] : whh1[n*128 + (kk - 128)];
      w1f[e2] = (_Float16)v;
    } else if (e < N0 + N1 + 1024) {
      int i = e - (N0 + N1);
      if (i < 512) bias0[i] = bih0[i] + bhh0[i];
      else         bias1[i - 512] = bih1[i - 512] + bhh1[i - 512];
    } else {
      prog[e - (N0 + N1 + 1024)] = 0;    // producer progress flags
    }
  }
}

// M-packing: 4 batch rows per block at A-rows m = 4*r (r=0..3).
//   Input batch: 4 steps x 4 rows = 16 full M-rows, m = dt*4 + r.
//   C/D: row = (lane>>4)*4 + reg -> rows {0,4,8,12} all in REG 0,
//   lane groups 0-15/16-31/32-47/48-63 -> epilogue: 64 lanes, 1 chain each.
// Compact recurrent A-frags: element (r, k): [kt= k>>5][ (k&31)>>3 * 4 + r ], byte k&7.
//   Reader lane L active iff (L&3)==0; cIdx = (L>>4)*4 + ((L>>2)&3).
//   Inactive lanes' A regs zero-init once, never written.
// Producer/consumer: blocks 0..127 = layer0 rows 4b..4b+3 -> h1buf;
//   blocks 128..255 = layer1 same rows. prog[pair] = #8-step batches of h1 done.

__global__ __launch_bounds__(512, 2) void lstm_fused(
    const float* __restrict__ x,
    const _Float16* __restrict__ w0f, const float* __restrict__ bias0,
    const _Float16* __restrict__ w1f, const float* __restrict__ bias1,
    const float* __restrict__ wlin, const float* __restrict__ blin,
    _Float16* __restrict__ h1buf, int* __restrict__ prog,
    float* __restrict__ out)
{
  __shared__ __align__(16) char smem[88064];
  const int tid = threadIdx.x;
  const int lane = tid & 63;
  const int w = tid >> 6;

  // common geometry
  const int sdt = tid >> 7, sr2 = (tid >> 5) & 3;      // staging: step-in-batch, row
  const bool arow = (lane & 3) == 0;
  const int cIdx = (lane >> 4)*4 + ((lane >> 2) & 3);
  const int rb = lane >> 4;                            // epilogue batch row 0..3
  const int en = w*16 + (lane & 15);                   // gate column 0..127
  const int eoff = ((en>>5)*16 + ((en&31)>>3)*4 + rb)*8 + (en&7);

  if (blockIdx.x < 128) {
    // ================= layer 0 (producer) =================
    const int pair = blockIdx.x;
    const int r0 = pair * 4;
    float* preLDS  = (float*)smem;                     // 2 x 8192 f32 (64 KB)
    half8* aF      = (half8*)(smem + 65536);           // 2 x 128 frags (4 KB)
    half8* hA      = (half8*)(smem + 69632);           // 2 x 64 frags (2 KB)
    _Float16* hist = (_Float16*)(smem + 71680);        // 16 x 4 x 128 (16 KB)

    for (int i = tid; i < 512; i += 512) ((int*)hA)[i] = 0;

    half8 bf[6][4];
#pragma unroll
    for (int kt = 0; kt < 6; ++kt)
#pragma unroll
      for (int g = 0; g < 4; ++g) {
        int frag = kt*32 + (g*8 + w);
        bf[kt][g] = *reinterpret_cast<const half8*>(w0f + (size_t)(frag*64 + lane)*8);
        asm volatile("" : "+a"(bf[kt][g]));
      }
    float bias_v[4];
#pragma unroll
    for (int g = 0; g < 4; ++g) bias_v[g] = bias0[g*128 + w*16 + (lane & 15)];

    const int scp = (tid & 31) * 2;
    const int sm = sdt*4 + sr2;
    const int sidx = ((scp>>5)*64 + sm + (((scp&31)>>3)<<4))*8 + (scp & 7);
    float cst = 0.f;

    // prologue: stage batches 0,1; pre batch 0
#pragma unroll
    for (int bb = 0; bb < 2; ++bb) {
      float2 v = *reinterpret_cast<const float2*>(x + ((size_t)(r0+sr2)*512 + bb*4 + sdt)*64 + scp);
      half2v hv; hv[0] = (_Float16)v.x; hv[1] = (_Float16)v.y;
      *reinterpret_cast<half2v*>(((_Float16*)(aF + bb*128)) + sidx) = hv;
    }
    __syncthreads();
    {
      floatx4 accP[4];
#pragma unroll
      for (int g = 0; g < 4; ++g) { float bb = bias_v[g]; accP[g] = (floatx4){bb,bb,bb,bb}; }
#pragma unroll
      for (int kt = 0; kt < 2; ++kt) {
        half8 af = aF[0*128 + kt*64 + lane];
#pragma unroll
        for (int g = 0; g < 4; ++g)
          accP[g] = __builtin_amdgcn_mfma_f32_16x16x32_f16(af, bf[kt][g], accP[g], 0, 0, 0);
      }
#pragma unroll
      for (int reg = 0; reg < 4; ++reg) {
        int m = (lane>>4)*4 + reg;
        floatx4 pv = (floatx4){accP[0][reg], accP[1][reg], accP[2][reg], accP[3][reg]};
        *reinterpret_cast<floatx4*>(&preLDS[(m*128 + en)*4]) = pv;
      }
    }
    __syncthreads();

    half8 a2 = {}, a3 = {}, a4 = {}, a5 = {};

    for (int t = 0; t < 512; ++t) {
      const int b = t >> 2;
      if ((t & 3) == 0 && b < 126) {       // stage batch b+2 -> aF[b&1]
        int s = (b+2)*4 + sdt;
        float2 v = *reinterpret_cast<const float2*>(x + ((size_t)(r0+sr2)*512 + s)*64 + scp);
        half2v hv; hv[0] = (_Float16)v.x; hv[1] = (_Float16)v.y;
        *reinterpret_cast<half2v*>(((_Float16*)(aF + (b&1)*128)) + sidx) = hv;
      }
      __syncthreads();
      if ((t & 7) == 1 && t >= 9 && tid == 0)   // flag: all fences of t-1 flush passed barrier
        __hip_atomic_store(&prog[pair], (t-1) >> 3, __ATOMIC_RELEASE, __HIP_MEMORY_SCOPE_AGENT);
      if ((t & 3) == 0) {
        if ((t & 7) == 0 && t != 0) {      // flush steps t-8..t-1 + device fence
          int tbase = t - 8;
          int fdt = tid >> 6, fr = (tid >> 4) & 3, n = (tid & 15) * 8;
          half8 v = *reinterpret_cast<const half8*>(&hist[(((tbase+fdt)&15)*4 + fr)*128 + n]);
          *reinterpret_cast<half8*>(h1buf + ((size_t)(r0+fr)*512 + tbase+fdt)*128 + n) = v;
          __threadfence();
        }
        if (b < 127) {                     // pre batch b+1 -> preLDS[(b+1)&1]
          int slot = (b+1) & 1;
          floatx4 accP[4];
#pragma unroll
          for (int g = 0; g < 4; ++g) { float bb = bias_v[g]; accP[g] = (floatx4){bb,bb,bb,bb}; }
#pragma unroll
          for (int kt = 0; kt < 2; ++kt) {
            half8 af = aF[slot*128 + kt*64 + lane];
#pragma unroll
            for (int g = 0; g < 4; ++g)
              accP[g] = __builtin_amdgcn_mfma_f32_16x16x32_f16(af, bf[kt][g], accP[g], 0, 0, 0);
          }
#pragma unroll
          for (int reg = 0; reg < 4; ++reg) {
            int m = (lane>>4)*4 + reg;
            floatx4 pv = (floatx4){accP[0][reg], accP[1][reg], accP[2][reg], accP[3][reg]};
            *reinterpret_cast<floatx4*>(&preLDS[slot*8192 + (m*128 + en)*4]) = pv;
          }
        }
      }

      floatx4 p4 = *reinterpret_cast<const floatx4*>(
          &preLDS[(b&1)*8192 + (((t&3)*4 + rb)*128 + en)*4]);
      floatx4 acc[4];
#pragma unroll
      for (int g = 0; g < 4; ++g) acc[g] = (floatx4){p4[g], 0.f, 0.f, 0.f};

      const int cur = t & 1;
      if (arow) {
        a2 = hA[cur*64 + 0*16 + cIdx];
        a3 = hA[cur*64 + 1*16 + cIdx];
        a4 = hA[cur*64 + 2*16 + cIdx];
        a5 = hA[cur*64 + 3*16 + cIdx];
      }
#pragma unroll
      for (int g = 0; g < 4; ++g)
        acc[g] = __builtin_amdgcn_mfma_f32_16x16x32_f16(a2, bf[2][g], acc[g], 0, 0, 0);
#pragma unroll
      for (int g = 0; g < 4; ++g)
        acc[g] = __builtin_amdgcn_mfma_f32_16x16x32_f16(a3, bf[3][g], acc[g], 0, 0, 0);
#pragma unroll
      for (int g = 0; g < 4; ++g)
        acc[g] = __builtin_amdgcn_mfma_f32_16x16x32_f16(a4, bf[4][g], acc[g], 0, 0, 0);
#pragma unroll
      for (int g = 0; g < 4; ++g)
        acc[g] = __builtin_amdgcn_mfma_f32_16x16x32_f16(a5, bf[5][g], acc[g], 0, 0, 0);

      {
        float ii = fast_sigmoid(acc[0][0]);
        float ff = fast_sigmoid(acc[1][0]);
        float gg = fast_tanh(acc[2][0]);
        float oo = fast_sigmoid(acc[3][0]);
        cst = ff*cst + ii*gg;
        float hv2 = oo*fast_tanh(cst);
        _Float16 hh = (_Float16)hv2;
        ((_Float16*)hA)[(cur^1)*512 + eoff] = hh;
        hist[((t&15)*4 + rb)*128 + en] = hh;
      }
    }
    __syncthreads();
    {                                      // final flush 504..511
      int tbase = 504;
      int fdt = tid >> 6, fr = (tid >> 4) & 3, n = (tid & 15) * 8;
      half8 v = *reinterpret_cast<const half8*>(&hist[(((tbase+fdt)&15)*4 + fr)*128 + n]);
      *reinterpret_cast<half8*>(h1buf + ((size_t)(r0+fr)*512 + tbase+fdt)*128 + n) = v;
      __threadfence();
    }
    __syncthreads();
    if (tid == 0)
      __hip_atomic_store(&prog[pair], 64, __ATOMIC_RELEASE, __HIP_MEMORY_SCOPE_AGENT);

  } else {
    // ================= layer 1 (consumer) + fused head =================
    const int pair = blockIdx.x - 128;
    const int r0 = pair * 4;
    float* preLDS = (float*)smem;                      // 64 KB
    half8* aF     = (half8*)(smem + 65536);            // 2 x 256 frags (8 KB)
    half8* hA     = (half8*)(smem + 73728);            // 2 KB
    float* head   = (float*)(smem + 75776);            // 512 f32

    for (int i = tid; i < 512; i += 512) ((int*)hA)[i] = 0;

    half8 bf[8][4];
#pragma unroll
    for (int kt = 0; kt < 8; ++kt)
#pragma unroll
      for (int g = 0; g < 4; ++g) {
        int frag = kt*32 + (g*8 + w);
        bf[kt][g] = *reinterpret_cast<const half8*>(w1f + (size_t)(frag*64 + lane)*8);
        asm volatile("" : "+a"(bf[kt][g]));
      }
    float bias_v[4];
#pragma unroll
    for (int g = 0; g < 4; ++g) bias_v[g] = bias1[g*128 + w*16 + (lane & 15)];

    const int scq = (tid & 31) * 4;
    const int sm = sdt*4 + sr2;
    const int sidx = ((scq>>5)*64 + sm + (((scq&31)>>3)<<4))*8 + (scq & 7);
    const float wl = wlin[en];
    float cst = 0.f, hl = 0.f;

    // prologue: wait for first h1 batch, stage batches 0,1; pre batch 0
    while (__hip_atomic_load(&prog[pair], __ATOMIC_ACQUIRE, __HIP_MEMORY_SCOPE_AGENT) < 1) {}
#pragma unroll
    for (int bb = 0; bb < 2; ++bb) {
      uint2 v = *reinterpret_cast<const uint2*>(h1buf + ((size_t)(r0+sr2)*512 + bb*4 + sdt)*128 + scq);
      *reinterpret_cast<uint2*>(((_Float16*)(aF + bb*256)) + sidx) = v;
    }
    __syncthreads();
    {
      floatx4 accP[4];
#pragma unroll
      for (int g = 0; g < 4; ++g) { float bb = bias_v[g]; accP[g] = (floatx4){bb,bb,bb,bb}; }
#pragma unroll
      for (int kt = 0; kt < 4; ++kt) {
        half8 af = aF[0*256 + kt*64 + lane];
#pragma unroll
        for (int g = 0; g < 4; ++g)
          accP[g] = __builtin_amdgcn_mfma_f32_16x16x32_f16(af, bf[kt][g], accP[g], 0, 0, 0);
      }
#pragma unroll
      for (int reg = 0; reg < 4; ++reg) {
        int m = (lane>>4)*4 + reg;
        floatx4 pv = (floatx4){accP[0][reg], accP[1][reg], accP[2][reg], accP[3][reg]};
        *reinterpret_cast<floatx4*>(&preLDS[(m*128 + en)*4]) = pv;
      }
    }
    __syncthreads();

    half8 a4 = {}, a5 = {}, a6 = {}, a7 = {};

    for (int t = 0; t < 512; ++t) {
      const int b = t >> 2;
      if ((t & 3) == 0 && b < 126) {       // wait for h1, stage batch b+2
        int need = (b + 4) >> 1;
        while (__hip_atomic_load(&prog[pair], __ATOMIC_ACQUIRE, __HIP_MEMORY_SCOPE_AGENT) < need) {}
        int s = (b+2)*4 + sdt;
        uint2 v = *reinterpret_cast<const uint2*>(h1buf + ((size_t)(r0+sr2)*512 + s)*128 + scq);
        *reinterpret_cast<uint2*>(((_Float16*)(aF + (b&1)*256)) + sidx) = v;
      }
      __syncthreads();
      if ((t & 3) == 0 && b < 127) {       // pre batch b+1
        int slot = (b+1) & 1;
        floatx4 accP[4];
#pragma unroll
        for (int g = 0; g < 4; ++g) { float bb = bias_v[g]; accP[g] = (floatx4){bb,bb,bb,bb}; }
#pragma unroll
        for (int kt = 0; kt < 4; ++kt) {
          half8 af = aF[slot*256 + kt*64 + lane];
#pragma unroll
          for (int g = 0; g < 4; ++g)
            accP[g] = __builtin_amdgcn_mfma_f32_16x16x32_f16(af, bf[kt][g], accP[g], 0, 0, 0);
        }
#pragma unroll
        for (int reg = 0; reg < 4; ++reg) {
          int m = (lane>>4)*4 + reg;
          floatx4 pv = (floatx4){accP[0][reg], accP[1][reg], accP[2][reg], accP[3][reg]};
          *reinterpret_cast<floatx4*>(&preLDS[slot*8192 + (m*128 + en)*4]) = pv;
        }
      }

      floatx4 p4 = *reinterpret_cast<const floatx4*>(
          &preLDS[(b&1)*8192 + (((t&3)*4 + rb)*128 + en)*4]);
      floatx4 acc[4];
#pragma unroll
      for (int g = 0; g < 4; ++g) acc[g] = (floatx4){p4[g], 0.f, 0.f, 0.f};

      const int cur = t & 1;
      if (arow) {
        a4 = hA[cur*64 + 0*16 + cIdx];
        a5 = hA[cur*64 + 1*16 + cIdx];
        a6 = hA[cur*64 + 2*16 + cIdx];
        a7 = hA[cur*64 + 3*16 + cIdx];
      }
#pragma unroll
      for (int g = 0; g < 4; ++g)
        acc[g] = __builtin_amdgcn_mfma_f32_16x16x32_f16(a4, bf[4][g], acc[g], 0, 0, 0);
#pragma unroll
      for (int g = 0; g < 4; ++g)
        acc[g] = __builtin_amdgcn_mfma_f32_16x16x32_f16(a5, bf[5][g], acc[g], 0, 0, 0);
#pragma unroll
      for (int g = 0; g < 4; ++g)
        acc[g] = __builtin_amdgcn_mfma_f32_16x16x32_f16(a6, bf[6][g], acc[g], 0, 0, 0);
#pragma unroll
      for (int g = 0; g < 4; ++g)
        acc[g] = __builtin_amdgcn_mfma_f32_16x16x32_f16(a7, bf[7][g], acc[g], 0, 0, 0);

      {
        float ii = fast_sigmoid(acc[0][0]);
        float ff = fast_sigmoid(acc[1][0]);
        float gg = fast_tanh(acc[2][0]);
        float oo = fast_sigmoid(acc[3][0]);
        cst = ff*cst + ii*gg;
        hl = oo*fast_tanh(cst);
        ((_Float16*)hA)[(cur^1)*512 + eoff] = (_Float16)hl;
      }
    }

    // fused head: out[r] = sum_n h_last[r][n]*wlin[n] + blin
    head[rb*128 + en] = hl * wl;
    __syncthreads();
    if (tid < 4) {
      float s = blin[0];
      for (int n = 0; n < 128; ++n) s += head[tid*128 + n];
      out[r0 + tid] = s;
    }
  }
}

extern "C" void kernel_launch(void* const* d_in, const int* in_sizes, int n_in,
                              void* d_out, int out_size, void* d_ws, size_t ws_size,
                              hipStream_t stream)
{
  const float* x    = (const float*)d_in[0];
  const float* wih0 = (const float*)d_in[1];
  const float* whh0 = (const float*)d_in[2];
  const float* bih0 = (const float*)d_in[3];
  const float* bhh0 = (const float*)d_in[4];
  const float* wih1 = (const float*)d_in[5];
  const float* whh1 = (const float*)d_in[6];
  const float* bih1 = (const float*)d_in[7];
  const float* bhh1 = (const float*)d_in[8];
  const float* wlin = (const float*)d_in[9];
  const float* blin = (const float*)d_in[10];
  float* out = (float*)d_out;

  char* ws = (char*)d_ws;
  _Float16* w0f = (_Float16*)(ws);               // 196608 B
  _Float16* w1f = (_Float16*)(ws + 196608);      // 262144 B
  float* bias0  = (float*)(ws + 458752);         // 2048 B
  float* bias1  = (float*)(ws + 460800);         // 2048 B
  int* prog     = (int*)(ws + 462848);           // 128 ints
  _Float16* h1  = (_Float16*)(ws + 1048576);     // 64 MB inter-layer buffer

  prep_kernel<<<256, 256, 0, stream>>>(wih0, whh0, bih0, bhh0, wih1, whh1, bih1, bhh1,
                                       w0f, w1f, bias0, bias1, prog);

  void* args[] = { (void*)&x, (void*)&w0f, (void*)&bias0, (void*)&w1f, (void*)&bias1,
                   (void*)&wlin, (void*)&blin, (void*)&h1, (void*)&prog, (void*)&out };
  hipLaunchCooperativeKernel((void*)lstm_fused, dim3(256), dim3(512), args, 0, stream);
}